// Round 1
// baseline (301.815 us; speedup 1.0000x reference)
//
#include <hip/hip_runtime.h>
#include <hip/hip_bf16.h>

typedef short short8 __attribute__((ext_vector_type(8)));
typedef float f32x4 __attribute__((ext_vector_type(4)));

#define MFMA(a, b, c) __builtin_amdgcn_mfma_f32_16x16x32_bf16((a), (b), (c), 0, 0, 0)

#define NB 2
#define NS 1024
#define NHID 768
#define NHEAD 12
#define NDH 64

__device__ __forceinline__ short f2bf(float x) {
    __hip_bfloat16 h = __float2bfloat16(x);
    return *reinterpret_cast<short*>(&h);
}

// load 8 consecutive f32, convert to bf16 fragment (A/B frag: lane holds 8
// contiguous k: k = (lane>>4)*8 + e  [guide §3 / m92 refcheck'd pattern])
__device__ __forceinline__ short8 ld8f32_bf(const float* __restrict__ p) {
    const f32x4* q = reinterpret_cast<const f32x4*>(p);
    f32x4 a = q[0], b = q[1];
    short8 r;
    r[0] = f2bf(a[0]); r[1] = f2bf(a[1]); r[2] = f2bf(a[2]); r[3] = f2bf(a[3]);
    r[4] = f2bf(b[0]); r[5] = f2bf(b[1]); r[6] = f2bf(b[2]); r[7] = f2bf(b[3]);
    return r;
}

// ---------------------------------------------------------------------------
// Kernel 1: QKV projection.  y = hidden @ W.T + b  (three W's, N space 2304)
// Q,K stored row-major bf16 (2048 x 768). V stored transposed per head:
// VT[b][h][d][s]  (so PV B-fragments are contiguous 16B loads).
// Tile: M=64 (4 waves x 16), N=64. Direct global->register fragments.
// ---------------------------------------------------------------------------
__global__ __launch_bounds__(256, 2) void qkv_proj(
    const float* __restrict__ hidden,
    const float* __restrict__ Wq, const float* __restrict__ bq,
    const float* __restrict__ Wk, const float* __restrict__ bk,
    const float* __restrict__ Wv, const float* __restrict__ bv,
    short* __restrict__ Qo, short* __restrict__ Ko, short* __restrict__ VTo)
{
    const int lane = threadIdx.x & 63;
    const int wave = threadIdx.x >> 6;
    const int lg = lane >> 4, lr = lane & 15;

    const int m0 = blockIdx.x * 64 + wave * 16;      // 32 blocks
    const int n0 = blockIdx.y * 64;                  // 36 blocks, [0,2304)
    const int proj = n0 / NHID;                      // 0:Q 1:K 2:V (64 | 768)
    const int ncol0 = n0 % NHID;
    const float* W = proj == 0 ? Wq : (proj == 1 ? Wk : Wv);
    const float* bias = proj == 0 ? bq : (proj == 1 ? bk : bv);

    f32x4 acc[4];
    #pragma unroll
    for (int s = 0; s < 4; ++s) acc[s] = (f32x4){0.f, 0.f, 0.f, 0.f};

    const float* arow = hidden + (size_t)(m0 + lr) * NHID;
    for (int k0 = 0; k0 < NHID; k0 += 32) {
        short8 afrag = ld8f32_bf(arow + k0 + lg * 8);
        #pragma unroll
        for (int s = 0; s < 4; ++s) {
            const float* bp = W + (size_t)(ncol0 + s * 16 + lr) * NHID + k0 + lg * 8;
            short8 bfrag = ld8f32_bf(bp);
            acc[s] = MFMA(afrag, bfrag, acc[s]);
        }
    }

    #pragma unroll
    for (int s = 0; s < 4; ++s) {
        const int ncol = ncol0 + s * 16 + lr;
        const float badd = bias[ncol];
        #pragma unroll
        for (int r = 0; r < 4; ++r) {
            const int m = m0 + lg * 4 + r;           // C: row=(l>>4)*4+r, col=l&15
            const short v16 = f2bf(acc[s][r] + badd);
            if (proj == 0) {
                Qo[(size_t)m * NHID + ncol] = v16;
            } else if (proj == 1) {
                Ko[(size_t)m * NHID + ncol] = v16;
            } else {
                const int b = m >> 10, ss = m & 1023;
                const int h = ncol >> 6, dd = ncol & 63;
                VTo[(((size_t)(b * NHEAD + h) * NDH + dd) << 10) + ss] = v16;
            }
        }
    }
}

// ---------------------------------------------------------------------------
// Kernel 2: fused attention with bbox bias (no-max softmax: scores are ~±4).
// wg = (b, 16 i-rows, j-chunk), 4 waves. Wave w owns heads {w, w+4, w+8} and
// bias rows i_local {4w..4w+3}. bbox read once (shared across heads via MFMA
// with M=heads). Partial num/den per chunk written to ws.
// ---------------------------------------------------------------------------
__global__ __launch_bounds__(256, 2) void attn(
    const short* __restrict__ Q,      // (2,1024,768) bf16
    const short* __restrict__ K,      // (2,1024,768) bf16
    const short* __restrict__ VT,     // (2,12,64,1024) bf16
    const float* __restrict__ bbox,   // (1024,1024,2,64) f32
    const float* __restrict__ mask,   // (2,1024) f32
    float* __restrict__ numw,         // (jc,2,12,1024,64)
    float* __restrict__ denw,         // (jc,2,12,1024)
    const int jc)
{
    const int it = blockIdx.x;        // 64 i-tiles
    const int b = blockIdx.y;         // 2
    const int c = blockIdx.z;         // jc chunks
    const int i0 = it * 16;
    const int jchunk = NS / jc;
    const int j_begin = c * jchunk;
    const int ntiles = jchunk / 32;

    const int lane = threadIdx.x & 63;
    const int wave = threadIdx.x >> 6;
    const int lg = lane >> 4, lr = lane & 15;

    __shared__ float blds[2][16][32][13];   // [buf][i_local][j_local][head] (+pad)
    __shared__ short plds[4][16][40];       // per-wave P scratch (pad 8)

    // ---- preload q fragments (reused over all j) ----
    short8 qk_a[3][2];   // [head][k-half]: A[m=i][k=d]
    #pragma unroll
    for (int hh = 0; hh < 3; ++hh) {
        const int h = wave + hh * 4;
        #pragma unroll
        for (int kk = 0; kk < 2; ++kk) {
            const short* p = Q + ((size_t)(b * NS) + i0 + lr) * NHID + h * 64 + kk * 32 + lg * 8;
            qk_a[hh][kk] = *reinterpret_cast<const short8*>(p);
        }
    }
    short8 bias_a[4][2]; // [i_local in wave's 4][k-half]: A[m=head][k=d]
    #pragma unroll
    for (int ii = 0; ii < 4; ++ii) {
        const int i = i0 + wave * 4 + ii;
        #pragma unroll
        for (int kk = 0; kk < 2; ++kk) {
            // reads lr*64 .. +63; lr up to 15 -> offset up to 1023 (benign
            // overread into following rows/K region, rows n>=12 are dropped)
            const short* p = Q + ((size_t)(b * NS) + i) * NHID + lr * 64 + kk * 32 + lg * 8;
            bias_a[ii][kk] = *reinterpret_cast<const short8*>(p);
        }
    }

    f32x4 ctx[3][4];
    #pragma unroll
    for (int hh = 0; hh < 3; ++hh)
        #pragma unroll
        for (int dt = 0; dt < 4; ++dt) ctx[hh][dt] = (f32x4){0.f, 0.f, 0.f, 0.f};
    f32x4 den[3];
    #pragma unroll
    for (int hh = 0; hh < 3; ++hh) den[hh] = (f32x4){0.f, 0.f, 0.f, 0.f};

    for (int t = 0; t < ntiles; ++t) {
        const int j0 = j_begin + t * 32;
        const int buf = t & 1;

        // ---- bias MFMAs for this wave's 4 i-rows -> LDS ----
        #pragma unroll
        for (int ii = 0; ii < 4; ++ii) {
            const int il = wave * 4 + ii;
            const int i = i0 + il;
            const float* bb = bbox + ((size_t)i * NS) * (NB * NDH) + (size_t)b * NDH;
            #pragma unroll
            for (int s = 0; s < 2; ++s) {
                f32x4 cbias = (f32x4){0.f, 0.f, 0.f, 0.f};
                #pragma unroll
                for (int kk = 0; kk < 2; ++kk) {
                    const float* p = bb + (size_t)(j0 + s * 16 + lr) * (NB * NDH) + kk * 32 + lg * 8;
                    short8 bfrag = ld8f32_bf(p);
                    cbias = MFMA(bias_a[ii][kk], bfrag, cbias);
                }
                const int jl = s * 16 + lr;
                #pragma unroll
                for (int r = 0; r < 4; ++r) {
                    const int n = lg * 4 + r;        // head row
                    if (n < NHEAD) blds[buf][il][jl][n] = cbias[r];
                }
            }
        }
        __syncthreads();   // bias tile visible; also separates reads(t-1) from writes(t+1)

        // ---- per-head: QK^T, +bias, exp, den, PV ----
        #pragma unroll
        for (int hh = 0; hh < 3; ++hh) {
            const int h = wave + hh * 4;
            f32x4 sc[2];
            #pragma unroll
            for (int s = 0; s < 2; ++s) {
                f32x4 c2 = (f32x4){0.f, 0.f, 0.f, 0.f};
                #pragma unroll
                for (int kk = 0; kk < 2; ++kk) {
                    const short* p = K + ((size_t)(b * NS) + j0 + s * 16 + lr) * NHID + h * 64 + kk * 32 + lg * 8;
                    short8 kfrag = *reinterpret_cast<const short8*>(p);
                    c2 = MFMA(qk_a[hh][kk], kfrag, c2);
                }
                sc[s] = c2;
            }
            const float mk0 = mask[b * NS + j0 + lr];
            const float mk1 = mask[b * NS + j0 + 16 + lr];
            #pragma unroll
            for (int s = 0; s < 2; ++s) {
                const float mk = s == 0 ? mk0 : mk1;
                #pragma unroll
                for (int r = 0; r < 4; ++r) {
                    const int il = lg * 4 + r;
                    const float v = (sc[s][r] + blds[buf][il][s * 16 + lr][h]) * 0.125f + mk;
                    sc[s][r] = __expf(v);
                }
            }
            den[hh] += sc[0] + sc[1];

            // P -> per-wave LDS (C-layout write), read back as A-frag (no
            // barrier needed: same-wave DS ops are in-order; clobbers pin order)
            #pragma unroll
            for (int s = 0; s < 2; ++s)
                #pragma unroll
                for (int r = 0; r < 4; ++r)
                    plds[wave][lg * 4 + r][s * 16 + lr] = f2bf(sc[s][r]);
            asm volatile("" ::: "memory");
            short8 pa = *reinterpret_cast<const short8*>(&plds[wave][lr][lg * 8]);
            asm volatile("" ::: "memory");

            #pragma unroll
            for (int dt = 0; dt < 4; ++dt) {
                const short* p = VT + ((size_t)(b * NHEAD + h) * NDH + dt * 16 + lr) * NS + j0 + lg * 8;
                short8 vfrag = *reinterpret_cast<const short8*>(p);
                ctx[hh][dt] = MFMA(pa, vfrag, ctx[hh][dt]);
            }
        }
    }

    // ---- den: reduce across the 16 j-lanes ----
    #pragma unroll
    for (int hh = 0; hh < 3; ++hh) {
        #pragma unroll
        for (int w = 1; w < 16; w <<= 1) {
            f32x4 o;
            #pragma unroll
            for (int r = 0; r < 4; ++r) o[r] = __shfl_xor(den[hh][r], w, 64);
            den[hh] += o;
        }
    }

    // ---- store partials ----
    #pragma unroll
    for (int hh = 0; hh < 3; ++hh) {
        const int h = wave + hh * 4;
        #pragma unroll
        for (int dt = 0; dt < 4; ++dt) {
            #pragma unroll
            for (int r = 0; r < 4; ++r) {
                const int i = i0 + lg * 4 + r;
                numw[(((size_t)(c * NB + b) * NHEAD + h) * NS + i) * NDH + dt * 16 + lr] = ctx[hh][dt][r];
            }
        }
        if (lr == 0) {
            #pragma unroll
            for (int r = 0; r < 4; ++r) {
                const int i = i0 + lg * 4 + r;
                denw[((size_t)(c * NB + b) * NHEAD + h) * NS + i] = den[hh][r];
            }
        }
    }
}

// ---------------------------------------------------------------------------
// Kernel 3: combine chunk partials:  out = sum_c num / sum_c den
// out layout (b, s, h*64+d)  == reference ctx reshape
// ---------------------------------------------------------------------------
__global__ void combine(const float* __restrict__ numw, const float* __restrict__ denw,
                        float* __restrict__ out, const int jc)
{
    const int idx = blockIdx.x * 256 + threadIdx.x;
    const int total = NB * NS * NHID;
    if (idx >= total) return;
    const int col = idx % NHID;
    const int row = idx / NHID;            // b*1024+s
    const int b = row >> 10, s = row & 1023;
    const int h = col >> 6, d = col & 63;
    float n = 0.f, dn = 0.f;
    for (int c = 0; c < jc; ++c) {
        n  += numw[(((size_t)(c * NB + b) * NHEAD + h) * NS + s) * NDH + d];
        dn += denw[((size_t)(c * NB + b) * NHEAD + h) * NS + s];
    }
    out[idx] = n / dn;
}

extern "C" void kernel_launch(void* const* d_in, const int* in_sizes, int n_in,
                              void* d_out, int out_size, void* d_ws, size_t ws_size,
                              hipStream_t stream) {
    (void)in_sizes; (void)n_in; (void)out_size;
    const float* hidden = (const float*)d_in[0];
    const float* bbox   = (const float*)d_in[1];
    const float* mask   = (const float*)d_in[2];
    const float* Wq = (const float*)d_in[3]; const float* bq = (const float*)d_in[4];
    const float* Wk = (const float*)d_in[5]; const float* bk = (const float*)d_in[6];
    const float* Wv = (const float*)d_in[7]; const float* bv = (const float*)d_in[8];
    float* out = (float*)d_out;

    char* ws = (char*)d_ws;
    const size_t qkv_bytes = (size_t)NB * NS * NHID * sizeof(short); // 3,145,728
    short* Qw  = (short*)ws;
    short* Kw  = (short*)(ws + qkv_bytes);
    short* VTw = (short*)(ws + 2 * qkv_bytes);
    const size_t base = 3 * qkv_bytes;
    const size_t num_per_chunk = (size_t)NB * NHEAD * NS * NDH * sizeof(float); // 6,291,456
    const size_t den_per_chunk = (size_t)NB * NHEAD * NS * sizeof(float);       //    98,304

    int jc = 8;
    while (jc > 1 && base + (size_t)jc * (num_per_chunk + den_per_chunk) > ws_size) jc >>= 1;
    float* numw = (float*)(ws + base);
    float* denw = (float*)(ws + base + (size_t)jc * num_per_chunk);

    dim3 gp(32, 36);
    qkv_proj<<<gp, 256, 0, stream>>>(hidden, Wq, bq, Wk, bk, Wv, bv, Qw, Kw, VTw);

    dim3 ga(64, NB, jc);
    attn<<<ga, 256, 0, stream>>>(Qw, Kw, VTw, bbox, mask, numw, denw, jc);

    const int total = NB * NS * NHID;
    combine<<<(total + 255) / 256, 256, 0, stream>>>(numw, denw, out, jc);
}